// Round 9
// baseline (171.892 us; speedup 1.0000x reference)
//
#include <hip/hip_runtime.h>
#include <stdint.h>

#define Nn 16384
#define Dd 128
#define Qq 4096
#define Ee 256
#define KV 64

typedef __bf16 bf16x8 __attribute__((ext_vector_type(8)));
typedef float floatx16 __attribute__((ext_vector_type(16)));
typedef unsigned uintx2 __attribute__((ext_vector_type(2)));

__device__ __forceinline__ float fexp2(float x) {
#if __has_builtin(__builtin_amdgcn_exp2f)
  return __builtin_amdgcn_exp2f(x);
#else
  return exp2f(x);
#endif
}
// pack two f32 -> bf16x2 (round-half-up, 3 VALU ops)
__device__ __forceinline__ unsigned pk_bf(float lo, float hi) {
  return __builtin_amdgcn_perm(__float_as_uint(hi) + 0x8000u,
                               __float_as_uint(lo) + 0x8000u, 0x07060302u);
}
// async global->LDS, 16B per lane; lds dest = wave-uniform base + lane*16
__device__ __forceinline__ void stage16(const void* g, void* lds_uniform) {
  __builtin_amdgcn_global_load_lds(
      (const __attribute__((address_space(1))) unsigned int*)g,
      (__attribute__((address_space(3))) unsigned int*)lds_uniform, 16, 0, 0);
}
// cross-half exchange
__device__ __forceinline__ void plswap(unsigned a, unsigned b, int hi,
                                       unsigned& r0, unsigned& r1) {
#if __has_builtin(__builtin_amdgcn_permlane32_swap)
  uintx2 r = __builtin_amdgcn_permlane32_swap(a, b, false, false);
  r0 = r[0];
  r1 = r[1];
  (void)hi;
#else
  unsigned ax = __shfl_xor(a, 32);
  unsigned bx = __shfl_xor(b, 32);
  r0 = hi ? bx : a;
  r1 = hi ? b : ax;
#endif
}
// hardware transpose read of one 4x16 bf16 subtile column.
// Semantics (m156+m162 joint model): supplied low 7 addr bits are the
// UNtransposed b64 row-slot (8B units); HW remaps (addr&127)>>2 and reads
// bytes (addr&~127) + ((addr&127)>>2) + 32*j, j=0..3 -> column (addr&127)/8.
__device__ __forceinline__ uintx2 tr16(const char* p) {
  unsigned a = (unsigned)(size_t)(const __attribute__((address_space(3))) char*)p;
  uintx2 r;
  asm volatile("ds_read_b64_tr_b16 %0, %1" : "=v"(r) : "v"(a));
  return r;
}

// ---- K1: fused LayerNorm + bf16 cast to subtiled xn + q/W cast -----------
// grid 512 = [b 2][tile 256 of 64 rows]; block 256.
// xn layout per 64x128 tile (16 KB): subtile ST(kvb=kv>>2, db=d>>4) at
// kvb*1024 + db*128 bytes; inside: row-major 4(kv) x 16(d) bf16.
// Serves BOTH S-phase b128 row-reads and PV tr_b16 column-reads.
__global__ __launch_bounds__(256) void k_lnt(
    const float* __restrict__ x, const float* __restrict__ gamma,
    const float* __restrict__ beta, const float* __restrict__ queries,
    const float* __restrict__ W, unsigned* __restrict__ xn,
    unsigned short* __restrict__ qb, unsigned short* __restrict__ wb) {
  const int tid = threadIdx.x;
  const int bid = blockIdx.x;
  const int b = bid >> 8, t = bid & 255;
  const int r = tid >> 2, qd = tid & 3;

  const float4* xp = (const float4*)(x + ((size_t)(b * Nn + t * 64 + r)) * Dd + qd * 32);
  float4 v[8];
  float s = 0.f, s2 = 0.f;
#pragma unroll
  for (int i = 0; i < 8; ++i) {
    v[i] = xp[i];
    s += (v[i].x + v[i].y) + (v[i].z + v[i].w);
    s2 += (v[i].x * v[i].x + v[i].y * v[i].y) + (v[i].z * v[i].z + v[i].w * v[i].w);
  }
  s += __shfl_xor(s, 1); s2 += __shfl_xor(s2, 1);
  s += __shfl_xor(s, 2); s2 += __shfl_xor(s2, 2);
  float mu = s * (1.0f / 128.0f);
  float var = s2 * (1.0f / 128.0f) - mu * mu;
  float rs = rsqrtf(var + 1e-5f);

  const float4* gp = (const float4*)(gamma + qd * 32);
  const float4* bp = (const float4*)(beta + qd * 32);
  unsigned pk[16];
#pragma unroll
  for (int i = 0; i < 8; ++i) {
    float4 g = gp[i], bt = bp[i];
    pk[2 * i] = pk_bf((v[i].x - mu) * rs * g.x + bt.x, (v[i].y - mu) * rs * g.y + bt.y);
    pk[2 * i + 1] = pk_bf((v[i].z - mu) * rs * g.z + bt.z, (v[i].w - mu) * rs * g.w + bt.w);
  }
  // subtile writes: dword base = kvb*256 + db*32 + (r&3)*8; pk[k] = d pair
  unsigned* tb = xn + ((size_t)(b * 256 + t)) * 4096;
  const int base = (r >> 2) * 256 + (r & 3) * 8;
  *(uint4*)(tb + base + (2 * qd) * 32) = make_uint4(pk[0], pk[1], pk[2], pk[3]);
  *(uint4*)(tb + base + (2 * qd) * 32 + 4) = make_uint4(pk[4], pk[5], pk[6], pk[7]);
  *(uint4*)(tb + base + (2 * qd + 1) * 32) = make_uint4(pk[8], pk[9], pk[10], pk[11]);
  *(uint4*)(tb + base + (2 * qd + 1) * 32 + 4) = make_uint4(pk[12], pk[13], pk[14], pk[15]);

  // fold-in: cast queries (prescaled) and W to bf16, vectorized
  const float QSC = 0.08838834764831845f * 1.4426950408889634f; // D^-0.5 * log2e
  const int total4 = (Qq * Dd + Ee * Dd) / 4;
  for (int u = bid * 256 + tid; u < total4; u += 512 * 256) {
    if (u < Qq * Dd / 4) {
      float4 v4 = ((const float4*)queries)[u];
      ((uint2*)qb)[u] = make_uint2(pk_bf(v4.x * QSC, v4.y * QSC),
                                   pk_bf(v4.z * QSC, v4.w * QSC));
    } else {
      float4 v4 = ((const float4*)W)[u - Qq * Dd / 4];
      ((uint2*)wb)[u - Qq * Dd / 4] =
          make_uint2(pk_bf(v4.x, v4.y), pk_bf(v4.z, v4.w));
    }
  }
}

// ---- K2: cross-attention, X-only LDS + hardware transpose PV -------------
// grid 512 = [b 2][qtile 16 of 256 q][split 16]; block 512 = 8 waves x 32 q.
// LDS: X triple-buffered 3x16KB = 48KB -> 2 blocks/CU, 16 waves/CU target.
// Per iter i (T15): S(i) MFMAs ; PV(i-1) via tr-reads ; exp(i).
// Counted vmcnt(2): never gates on freshly issued loads.
template <int NS, int NWAVE>
__global__ __launch_bounds__(NWAVE * 64, 2) void k_attn(
    const unsigned short* __restrict__ xn,   // [B][256 tiles][16KB subtiled]
    const unsigned short* __restrict__ qb,   // [Q][D] prescaled bf16
    float* __restrict__ o_part,              // [B][NS][Q][D]
    float* __restrict__ l_part) {            // [B][NS][Q]
  constexpr int NCH = Nn / NS;              // 1024 kv per split
  constexpr int NIT = NCH / KV;             // 16 tiles per block (even)
  constexpr int QT = Qq / (32 * NWAVE);     // 16 q-tiles
  constexpr int CPW = 16 / NWAVE;           // 2 staging chunks/wave
  __shared__ __align__(16) char lds_x[3][16384];

  const int bid = blockIdx.x;
  const int split = bid % NS;               // split%8 == XCD id -> L2-local
  const int qt = (bid / NS) % QT;
  const int b = bid / (NS * QT);
  const int tid = threadIdx.x;
  const int wave = tid >> 6, lane = tid & 63;
  const int col = lane & 31, half = lane >> 5;
  const int qwbase = qt * (32 * NWAVE) + wave * 32;

  // Q B-fragments in registers: n=col, k=half*8+j per 16-k step
  bf16x8 qf[8];
#pragma unroll
  for (int s = 0; s < 8; ++s)
    qf[s] = *(const bf16x8*)(qb + (size_t)(qwbase + col) * Dd + s * 16 + half * 8);

  const floatx16 fz = {0.f,0.f,0.f,0.f,0.f,0.f,0.f,0.f,0.f,0.f,0.f,0.f,0.f,0.f,0.f,0.f};
  floatx16 O[4];
#pragma unroll
  for (int d = 0; d < 4; ++d) O[d] = fz;
  float lsum = 0.f;

  const char* gx = (const char*)xn + (size_t)b * 256 * 16384;
  const int tbase = split * NIT;
  // S-phase lane-const part: subtile (c>>2), inner (c&3)*32 + h*16
  const int soff = (col >> 2) * 1024 + (col & 3) * 32 + half * 16;
  // PV lane-const part: kvb 2h (bytes half*2048), d-subtile (c>>4)*128,
  // column (c&15) supplied as UNtransposed row-slot: (c&15)*8  [H1 fix]
  const int pvoff = 2 * half * 1024 + (col >> 4) * 128 + (col & 15) * 8;

  auto stgX = [&](int t, int buf) {
    const char* src = gx + (size_t)(tbase + t) * 16384;
#pragma unroll
    for (int p = 0; p < CPW; ++p) {
      int m = wave * CPW + p;
      stage16(src + m * 1024 + lane * 16, &lds_x[buf][0] + m * 1024);
    }
  };
  // S^T[kv 64][q 32] = X(A) . Q^T(B); A row kv=32mt+col, d-chunk s*16+h*8
  auto sphase = [&](const char* lx, floatx16* S) {
#pragma unroll
    for (int s = 0; s < 8; ++s)
#pragma unroll
      for (int mt = 0; mt < 2; ++mt) {
        bf16x8 ax = *(const bf16x8*)(lx + soff + mt * 8192 + s * 128);
        S[mt] = __builtin_amdgcn_mfma_f32_32x32x16_bf16(ax, qf[s], S[mt], 0, 0, 0);
      }
  };
  // p = exp2(s); accumulate l; pack P[g][w]: kv = 8g+4*half+2w..
  auto exp_mt = [&](const floatx16& S, unsigned Pm[4][2]) {
#pragma unroll
    for (int t = 0; t < 4; ++t) {
      float p0 = fexp2(S[4 * t]);
      float p1 = fexp2(S[4 * t + 1]);
      float p2 = fexp2(S[4 * t + 2]);
      float p3 = fexp2(S[4 * t + 3]);
      lsum += (p0 + p1) + (p2 + p3);
      Pm[t][0] = pk_bf(p0, p1);
      Pm[t][1] = pk_bf(p2, p3);
    }
  };
  // one PV s2-step: A = P-frag (cross-half swap), B = X^T via 8 tr-reads
  auto pv_s2 = [&](const char* lxt, unsigned (&P)[2][4][2], int s2) {
    const int mt = s2 >> 1, ge = 2 * (s2 & 1), go = ge + 1;
    unsigned w0, w1, w2, w3;
    plswap(P[mt][ge][0], P[mt][go][0], half, w0, w2);
    plswap(P[mt][ge][1], P[mt][go][1], half, w1, w3);
    union { uint4 u; bf16x8 v; } ap;
    ap.u = make_uint4(w0, w1, w2, w3);
    const char* ab = lxt + pvoff + s2 * 4096;
    uintx2 t0a = tr16(ab);           uintx2 t0b = tr16(ab + 1024);
    uintx2 t1a = tr16(ab + 256);     uintx2 t1b = tr16(ab + 256 + 1024);
    uintx2 t2a = tr16(ab + 512);     uintx2 t2b = tr16(ab + 512 + 1024);
    uintx2 t3a = tr16(ab + 768);     uintx2 t3b = tr16(ab + 768 + 1024);
    asm volatile("s_waitcnt lgkmcnt(0)" ::);
    __builtin_amdgcn_sched_barrier(0);
    union { uint4 u; bf16x8 v; } bx;
    bx.u = make_uint4(t0a[0], t0a[1], t0b[0], t0b[1]);
    O[0] = __builtin_amdgcn_mfma_f32_32x32x16_bf16(ap.v, bx.v, O[0], 0, 0, 0);
    bx.u = make_uint4(t1a[0], t1a[1], t1b[0], t1b[1]);
    O[1] = __builtin_amdgcn_mfma_f32_32x32x16_bf16(ap.v, bx.v, O[1], 0, 0, 0);
    bx.u = make_uint4(t2a[0], t2a[1], t2b[0], t2b[1]);
    O[2] = __builtin_amdgcn_mfma_f32_32x32x16_bf16(ap.v, bx.v, O[2], 0, 0, 0);
    bx.u = make_uint4(t3a[0], t3a[1], t3b[0], t3b[1]);
    O[3] = __builtin_amdgcn_mfma_f32_32x32x16_bf16(ap.v, bx.v, O[3], 0, 0, 0);
  };

  int prev = 0, cur = 1;   // buffer of tile i-1 / tile i

  auto body = [&](int i, unsigned (&Pprev)[2][4][2], unsigned (&Pcur)[2][4][2]) {
    if (i + 1 < NIT) {
      asm volatile("s_waitcnt vmcnt(2)" ::: "memory");   // tile i resident
    } else {
      asm volatile("s_waitcnt vmcnt(0)" ::: "memory");
    }
    __builtin_amdgcn_s_barrier();
    __builtin_amdgcn_sched_barrier(0);

    const char* lx = &lds_x[cur][0];
    const char* lxt = &lds_x[prev][0];

    floatx16 S[2]; S[0] = fz; S[1] = fz;
    __builtin_amdgcn_s_setprio(1);
    sphase(lx, S);                      // stream 1: S(i)
    pv_s2(lxt, Pprev, 0);               // stream 2: PV(i-1)
    pv_s2(lxt, Pprev, 1);
    pv_s2(lxt, Pprev, 2);
    pv_s2(lxt, Pprev, 3);
    __builtin_amdgcn_s_setprio(0);
    exp_mt(S[0], Pcur[0]);              // P := P(i)
    exp_mt(S[1], Pcur[1]);

    asm volatile("" ::: "memory");
    __builtin_amdgcn_s_barrier();       // reads of X(i) and X(i-1) done
    if (i + 2 < NIT) stgX(i + 2, prev); // (i+2)%3 == (i-1)%3
    int nxt = (cur == 2) ? 0 : cur + 1;
    prev = cur; cur = nxt;
  };

  // prologue: tiles 0,1 in flight
  stgX(0, 0);
  stgX(1, 1);
  asm volatile("s_waitcnt vmcnt(2)" ::: "memory");   // tile 0 resident
  __builtin_amdgcn_s_barrier();
  __builtin_amdgcn_sched_barrier(0);

  unsigned PA[2][4][2], PB[2][4][2];
  {
    floatx16 S[2]; S[0] = fz; S[1] = fz;
    __builtin_amdgcn_s_setprio(1);
    sphase(&lds_x[0][0], S);
    __builtin_amdgcn_s_setprio(0);
    exp_mt(S[0], PA[0]);
    exp_mt(S[1], PA[1]);
  }
  asm volatile("" ::: "memory");
  __builtin_amdgcn_s_barrier();                      // X0 reads done
  if (NIT > 2) stgX(2, 2);

  // main loop: P ping-pong, pair-unrolled for static indexing (NIT even)
#pragma unroll 1
  for (int i = 1; i + 1 < NIT; i += 2) {
    body(i, PA, PB);
    body(i + 1, PB, PA);
  }
  body(NIT - 1, PA, PB);
  // final PV(NIT-1): its buffer is 'prev' after the last rotate
  pv_s2(&lds_x[prev][0], PB, 0);
  pv_s2(&lds_x[prev][0], PB, 1);
  pv_s2(&lds_x[prev][0], PB, 2);
  pv_s2(&lds_x[prev][0], PB, 3);

  // epilogue
  float lt = lsum + __shfl_xor(lsum, 32);
  if (half == 0)
    l_part[(size_t)(b * NS + split) * Qq + qwbase + col] = lt;
  float* op = o_part + ((size_t)(b * NS + split) * Qq + qwbase) * Dd;
#pragma unroll
  for (int dn = 0; dn < 4; ++dn)
#pragma unroll
    for (int r = 0; r < 16; ++r) {
      int q = (r & 3) + 8 * (r >> 2) + 4 * half;
      op[(size_t)q * Dd + dn * 32 + col] = O[dn][r];
    }
}

// ---- K3: combine splits, normalize, trailing GEMM (32x32x16) -------------
// grid 256 = [b 2][qchunk 128 of 32 q]; block 256 = 4 waves (wave owns 64 E)
template <int NS>
__global__ __launch_bounds__(256) void k_comb(
    const float* __restrict__ o_part, const float* __restrict__ l_part,
    const unsigned short* __restrict__ wb, float* __restrict__ out) {
  __shared__ __align__(16) char lds_a[32 * 256];
  __shared__ float lds_linv[32];
  const int bid = blockIdx.x;
  const int b = bid >> 7, qc = bid & 127;
  const int qbase = qc * 32;
  const int tid = threadIdx.x;
  const int wave = tid >> 6, lane = tid & 63;
  const int col = lane & 31, half = lane >> 5;
  const int ck = col & 7;

  if (tid < 32) {
    float l = 0.f;
#pragma unroll
    for (int s = 0; s < NS; ++s)
      l += l_part[(size_t)(b * NS + s) * Qq + qbase + tid];
    lds_linv[tid] = 1.0f / l;
  }
  __syncthreads();

#pragma unroll
  for (int i = 0; i < 4; ++i) {
    int idx = i * 256 + tid;      // 1024 float4 units: q = idx>>5, d4 = idx&31
    int q = idx >> 5, d4 = idx & 31;
    float4 acc = make_float4(0.f, 0.f, 0.f, 0.f);
#pragma unroll
    for (int s = 0; s < NS; ++s) {
      float4 v = *(const float4*)(o_part + ((size_t)(b * NS + s) * Qq + qbase + q) * Dd + d4 * 4);
      acc.x += v.x; acc.y += v.y; acc.z += v.z; acc.w += v.w;
    }
    float li = lds_linv[q];
    int w = d4 >> 1;                          // 16B unit = 8 d values
    int pos = (w & 8) | ((w ^ (q & 7)) & 7);  // swizzle low 3 bits only
    *(uint2*)(lds_a + q * 256 + pos * 16 + (d4 & 1) * 8) =
        make_uint2(pk_bf(acc.x * li, acc.y * li), pk_bf(acc.z * li, acc.w * li));
  }
  __syncthreads();

  bf16x8 af[8];
#pragma unroll
  for (int s = 0; s < 8; ++s) {
    int u = 2 * s + half;
    int pos = (u & 8) | ((u ^ ck) & 7);
    af[s] = *(const bf16x8*)(lds_a + col * 256 + pos * 16);
  }

  const floatx16 fz = {0.f,0.f,0.f,0.f,0.f,0.f,0.f,0.f,0.f,0.f,0.f,0.f,0.f,0.f,0.f,0.f};
#pragma unroll
  for (int et = 0; et < 2; ++et) {
    floatx16 C = fz;
    int e_row = wave * 64 + et * 32 + col;
#pragma unroll
    for (int s = 0; s < 8; ++s) {
      bf16x8 bw = *(const bf16x8*)(wb + (size_t)e_row * Dd + s * 16 + half * 8);
      C = __builtin_amdgcn_mfma_f32_32x32x16_bf16(af[s], bw, C, 0, 0, 0);
    }
#pragma unroll
    for (int r = 0; r < 16; ++r) {
      int q = qbase + (r & 3) + 8 * (r >> 2) + 4 * half;
      out[((size_t)b * Qq + q) * Ee + wave * 64 + et * 32 + col] = C[r];
    }
  }
}

// ---- launcher ------------------------------------------------------------
extern "C" void kernel_launch(void* const* d_in, const int* in_sizes, int n_in,
                              void* d_out, int out_size, void* d_ws, size_t ws_size,
                              hipStream_t stream) {
  const float* x = (const float*)d_in[0];
  const float* gamma = (const float*)d_in[1];
  const float* beta = (const float*)d_in[2];
  const float* queries = (const float*)d_in[3];
  const float* W = (const float*)d_in[4];
  float* out = (float*)d_out;

  char* w = (char*)d_ws;
  unsigned* xn = (unsigned*)(w);                              // 8 MB subtiled
  unsigned short* qb = (unsigned short*)(w + 8388608);        // 1 MB
  unsigned short* wb = (unsigned short*)(w + 9437184);        // 64 KB
  float* o_part = (float*)(w + 9502720);                      // 64 MB (NS=16)
  float* l_part = (float*)(w + 9502720 + 67108864);           // 512 KB

  k_lnt<<<dim3(512), dim3(256), 0, stream>>>(x, gamma, beta, queries, W,
                                             xn, qb, wb);
  // 2 b x 16 qt(256 q) x 16 splits = 512 blocks of 8 waves -> 2 blocks/CU
  k_attn<16, 8><<<dim3(512), dim3(512), 0, stream>>>(
      (const unsigned short*)xn, qb, o_part, l_part);
  k_comb<16><<<dim3(256), dim3(256), 0, stream>>>(o_part, l_part, wb, out);
}

// Round 10
// 158.414 us; speedup vs baseline: 1.0851x; 1.0851x over previous
//
#include <hip/hip_runtime.h>
#include <stdint.h>

#define Nn 16384
#define Dd 128
#define Qq 4096
#define Ee 256
#define KV 64

typedef __bf16 bf16x8 __attribute__((ext_vector_type(8)));
typedef float floatx16 __attribute__((ext_vector_type(16)));
typedef unsigned uintx2 __attribute__((ext_vector_type(2)));

__device__ __forceinline__ float fexp2(float x) {
#if __has_builtin(__builtin_amdgcn_exp2f)
  return __builtin_amdgcn_exp2f(x);
#else
  return exp2f(x);
#endif
}
// pack two f32 -> bf16x2 (round-half-up, 3 VALU ops)
__device__ __forceinline__ unsigned pk_bf(float lo, float hi) {
  return __builtin_amdgcn_perm(__float_as_uint(hi) + 0x8000u,
                               __float_as_uint(lo) + 0x8000u, 0x07060302u);
}
// async global->LDS, 16B per lane; lds dest = wave-uniform base + lane*16
__device__ __forceinline__ void stage16(const void* g, void* lds_uniform) {
  __builtin_amdgcn_global_load_lds(
      (const __attribute__((address_space(1))) unsigned int*)g,
      (__attribute__((address_space(3))) unsigned int*)lds_uniform, 16, 0, 0);
}
// cross-half exchange: h0 lane ends with (a_own, a_from_h1); h1 with (b_from_h0, b_own)
__device__ __forceinline__ void plswap(unsigned a, unsigned b, int hi,
                                       unsigned& r0, unsigned& r1) {
#if __has_builtin(__builtin_amdgcn_permlane32_swap)
  uintx2 r = __builtin_amdgcn_permlane32_swap(a, b, false, false);
  r0 = r[0];
  r1 = r[1];
  (void)hi;
#else
  unsigned ax = __shfl_xor(a, 32);
  unsigned bx = __shfl_xor(b, 32);
  r0 = hi ? bx : a;
  r1 = hi ? b : ax;
#endif
}

// ---- K1: fused LayerNorm + bf16 cast (swizzled) + transpose + q/W cast ---
// grid 512 = [b 2][ntile 256 of 64 rows]; block 256.
// xn global layout: row n (256B), 16B-unit c stored at c ^ (n&7).
// xnT global layout: row d (32KB), within each 64-n window unit g at g^(d&7).
__global__ __launch_bounds__(256) void k_lnt(
    const float* __restrict__ x, const float* __restrict__ gamma,
    const float* __restrict__ beta, const float* __restrict__ queries,
    const float* __restrict__ W, unsigned* __restrict__ xn,
    unsigned short* __restrict__ xnT, unsigned short* __restrict__ qb,
    unsigned short* __restrict__ wb) {
  __shared__ __align__(16) uint2 lds2[64 * 32];   // [row][d-quad], xor-swizzled
  const int tid = threadIdx.x;
  const int bid = blockIdx.x;
  const int b = bid >> 8, n0 = (bid & 255) * 64;
  const int r = tid >> 2, qd = tid & 3;

  const float4* xp = (const float4*)(x + ((size_t)(b * Nn + n0 + r)) * Dd + qd * 32);
  float4 v[8];
  float s = 0.f, s2 = 0.f;
#pragma unroll
  for (int i = 0; i < 8; ++i) {
    v[i] = xp[i];
    s += (v[i].x + v[i].y) + (v[i].z + v[i].w);
    s2 += (v[i].x * v[i].x + v[i].y * v[i].y) + (v[i].z * v[i].z + v[i].w * v[i].w);
  }
  s += __shfl_xor(s, 1); s2 += __shfl_xor(s2, 1);
  s += __shfl_xor(s, 2); s2 += __shfl_xor(s2, 2);
  float mu = s * (1.0f / 128.0f);
  float var = s2 * (1.0f / 128.0f) - mu * mu;
  float rs = rsqrtf(var + 1e-5f);

  const float4* gp = (const float4*)(gamma + qd * 32);
  const float4* bp = (const float4*)(beta + qd * 32);
  unsigned pk[16];
#pragma unroll
  for (int i = 0; i < 8; ++i) {
    float4 g = gp[i], bt = bp[i];
    pk[2 * i] = pk_bf((v[i].x - mu) * rs * g.x + bt.x, (v[i].y - mu) * rs * g.y + bt.y);
    pk[2 * i + 1] = pk_bf((v[i].z - mu) * rs * g.z + bt.z, (v[i].w - mu) * rs * g.w + bt.w);
  }
  // xn write: 16B unit c = qd*4+j stored at position c ^ (r&7)
  unsigned* xrow = xn + ((size_t)(b * Nn + n0 + r)) * 64;
#pragma unroll
  for (int j = 0; j < 4; ++j)
    *(uint4*)(xrow + (((qd * 4 + j) ^ (r & 7)) * 4)) =
        make_uint4(pk[4 * j], pk[4 * j + 1], pk[4 * j + 2], pk[4 * j + 3]);
  // LDS for transpose: uint2 unit m holds d = 4m..4m+3 of row r
  const int rk = r & 31;
#pragma unroll
  for (int kk = 0; kk < 8; ++kk)
    lds2[r * 32 + ((qd * 8 + kk) ^ rk)] = make_uint2(pk[2 * kk], pk[2 * kk + 1]);
  __syncthreads();
  // transpose: thread -> d-quad dq, n-group nc
  const int dq = tid >> 3, nc = tid & 7;
  uint2 U[8];
#pragma unroll
  for (int j = 0; j < 8; ++j) {
    int rr = nc * 8 + j;
    U[j] = lds2[rr * 32 + (dq ^ (rr & 31))];
  }
#pragma unroll
  for (int e = 0; e < 4; ++e) {
    int d = dq * 4 + e;
    unsigned a0 = (e & 2) ? U[0].y : U[0].x, a1 = (e & 2) ? U[1].y : U[1].x;
    unsigned a2 = (e & 2) ? U[2].y : U[2].x, a3 = (e & 2) ? U[3].y : U[3].x;
    unsigned a4 = (e & 2) ? U[4].y : U[4].x, a5 = (e & 2) ? U[5].y : U[5].x;
    unsigned a6 = (e & 2) ? U[6].y : U[6].x, a7 = (e & 2) ? U[7].y : U[7].x;
    unsigned sel = (e & 1) ? 0x07060302u : 0x05040100u;
    uint4 o;
    o.x = __builtin_amdgcn_perm(a1, a0, sel);
    o.y = __builtin_amdgcn_perm(a3, a2, sel);
    o.z = __builtin_amdgcn_perm(a5, a4, sel);
    o.w = __builtin_amdgcn_perm(a7, a6, sel);
    *(uint4*)(xnT + ((size_t)(b * Dd + d)) * Nn + n0 + (nc ^ (d & 7)) * 8) = o;
  }
  // fold-in: cast queries (prescaled) and W to bf16, vectorized
  const float QSC = 0.08838834764831845f * 1.4426950408889634f; // D^-0.5 * log2e
  const int total4 = (Qq * Dd + Ee * Dd) / 4;
  for (int u = bid * 256 + tid; u < total4; u += 512 * 256) {
    if (u < Qq * Dd / 4) {
      float4 v4 = ((const float4*)queries)[u];
      ((uint2*)qb)[u] = make_uint2(pk_bf(v4.x * QSC, v4.y * QSC),
                                   pk_bf(v4.z * QSC, v4.w * QSC));
    } else {
      float4 v4 = ((const float4*)W)[u - Qq * Dd / 4];
      ((uint2*)wb)[u - Qq * Dd / 4] =
          make_uint2(pk_bf(v4.x, v4.y), pk_bf(v4.z, v4.w));
    }
  }
}

// ---- K2: cross-attention, cross-iteration pipelined (T15) ----------------
// Per iter i: [vmcnt(8); barrier] S(i) MFMAs ∥ PV(i-1) MFMAs (independent
// streams) ; exp(i)->P ; [barrier] stage tile i+2.  The S->exp->P->PV chain
// spans two iterations instead of serializing inside one.
// LDS: X double-buffered (2x16KB, lifetime stage->S(t)) + Xt triple-buffered
// (3x16KB, lifetime stage->PV at t+1) = 80KB -> exactly 2 blocks/CU.
template <int NS, int NWAVE>
__global__ __launch_bounds__(NWAVE * 64, 2) void k_attn(
    const unsigned short* __restrict__ xn,   // [B][N][D] swizzled
    const unsigned short* __restrict__ xnT,  // [B][D][N] swizzled
    const unsigned short* __restrict__ qb,   // [Q][D] prescaled bf16
    float* __restrict__ o_part,              // [B][NS][Q][D]
    float* __restrict__ l_part) {            // [B][NS][Q]
  constexpr int NCH = Nn / NS;              // kv per split
  constexpr int NIT = NCH / KV;             // tiles per block (32)
  constexpr int QT = Qq / (32 * NWAVE);     // q-tiles
  constexpr int CPW = 16 / NWAVE;           // staging chunks/wave/tensor
  __shared__ __align__(16) char lds_x[2][16384];
  __shared__ __align__(16) char lds_xt[3][16384];

  const int bid = blockIdx.x;
  const int split = bid % NS;               // == XCD id under round-robin
  const int qt = (bid / NS) % QT;
  const int b = bid / (NS * QT);
  const int tid = threadIdx.x;
  const int wave = tid >> 6, lane = tid & 63;
  const int col = lane & 31, half = lane >> 5;
  const int ck = col & 7;
  const int qwbase = qt * (32 * NWAVE) + wave * 32;

  // Q B-fragments in registers: n=col, k=half*8+j per 16-k step
  bf16x8 qf[8];
#pragma unroll
  for (int s = 0; s < 8; ++s)
    qf[s] = *(const bf16x8*)(qb + (size_t)(qwbase + col) * Dd + s * 16 + half * 8);

  const floatx16 fz = {0.f,0.f,0.f,0.f,0.f,0.f,0.f,0.f,0.f,0.f,0.f,0.f,0.f,0.f,0.f,0.f};
  floatx16 O[4];
#pragma unroll
  for (int d = 0; d < 4; ++d) O[d] = fz;
  float lsum = 0.f;

  const char* gx = (const char*)xn + (size_t)b * Nn * 256;
  const char* gxt = (const char*)xnT + (size_t)b * Dd * Nn * 2;
  const int tbase = split * NCH / KV;

  auto stgX = [&](int t, int buf) {
    const char* xsrc = gx + (size_t)(tbase + t) * (KV * 256);
#pragma unroll
    for (int p = 0; p < CPW; ++p) {
      int m = wave * CPW + p;
      stage16(xsrc + m * 1024 + lane * 16, &lds_x[buf][0] + m * 1024);
    }
  };
  auto stgXT = [&](int t, int buf) {
#pragma unroll
    for (int p = 0; p < CPW; ++p) {
      int m = wave * CPW + p;
      const char* g = gxt + (size_t)(m * 8 + (lane >> 3)) * (Nn * 2) +
                      (size_t)(tbase + t) * (KV * 2) + (lane & 7) * 16;
      stage16(g, &lds_xt[buf][0] + m * 1024);
    }
  };
  // S^T[kv 64][q 32] = X(A) . Q^T(B)
  auto sphase = [&](const char* lx, floatx16* S) {
#pragma unroll
    for (int s = 0; s < 8; ++s)
#pragma unroll
      for (int mt = 0; mt < 2; ++mt) {
        bf16x8 ax = *(const bf16x8*)(lx + (32 * mt + col) * 256 +
                                     (((2 * s + half) ^ ck) * 16));
        S[mt] = __builtin_amdgcn_mfma_f32_32x32x16_bf16(ax, qf[s], S[mt], 0, 0, 0);
      }
  };
  // p = exp2(s); accumulate l; pack P[mt][g][w]: kv = 32mt+8g+4*half+2w..
  auto expphase = [&](const floatx16* S, unsigned P[2][4][2]) {
#pragma unroll
    for (int mt = 0; mt < 2; ++mt)
#pragma unroll
      for (int t = 0; t < 4; ++t) {
        float p0 = fexp2(S[mt][4 * t]);
        float p1 = fexp2(S[mt][4 * t + 1]);
        float p2 = fexp2(S[mt][4 * t + 2]);
        float p3 = fexp2(S[mt][4 * t + 3]);
        lsum += (p0 + p1) + (p2 + p3);
        P[mt][t][0] = pk_bf(p0, p1);
        P[mt][t][1] = pk_bf(p2, p3);
      }
  };
  // O[q 32][d 128] += P(A) . Xt(B); A-frag via cross-half swap
  auto pvphase = [&](const char* lxt, unsigned P[2][4][2]) {
#pragma unroll
    for (int s2 = 0; s2 < 4; ++s2) {
      const int mt = s2 >> 1, ge = 2 * (s2 & 1), go = ge + 1;
      unsigned w0, w1, w2, w3;
      plswap(P[mt][ge][0], P[mt][go][0], half, w0, w2);
      plswap(P[mt][ge][1], P[mt][go][1], half, w1, w3);
      union { uint4 u; bf16x8 v; } ap;
      ap.u = make_uint4(w0, w1, w2, w3);
#pragma unroll
      for (int dn = 0; dn < 4; ++dn) {
        bf16x8 bx = *(const bf16x8*)(lxt + (32 * dn + col) * 128 +
                                     (((2 * s2 + half) ^ ck) * 16));
        O[dn] = __builtin_amdgcn_mfma_f32_32x32x16_bf16(ap.v, bx, O[dn], 0, 0, 0);
      }
    }
  };

  // prologue: tiles 0,1 in flight
  stgX(0, 0); stgXT(0, 0);
  stgX(1, 1); stgXT(1, 1);
  asm volatile("s_waitcnt vmcnt(8)" ::: "memory");   // tile 0 resident
  __builtin_amdgcn_s_barrier();
  __builtin_amdgcn_sched_barrier(0);

  unsigned P[2][4][2];
  {
    floatx16 S[2]; S[0] = fz; S[1] = fz;
    __builtin_amdgcn_s_setprio(1);
    sphase(&lds_x[0][0], S);
    __builtin_amdgcn_s_setprio(0);
    expphase(S, P);
  }
  asm volatile("" ::: "memory");
  __builtin_amdgcn_s_barrier();                      // X0 reads done
  if (NIT > 2) { stgX(2, 0); stgXT(2, 2); }

  int xtc = 0;   // Xt buffer holding tile i-1
#pragma unroll 1
  for (int i = 1; i < NIT; ++i) {
    if (i + 1 < NIT) {
      asm volatile("s_waitcnt vmcnt(8)" ::: "memory");   // tile i resident
    } else {
      asm volatile("s_waitcnt vmcnt(0)" ::: "memory");
    }
    __builtin_amdgcn_s_barrier();
    __builtin_amdgcn_sched_barrier(0);

    const char* lx = &lds_x[i & 1][0];
    const char* lxt = &lds_xt[xtc][0];

    floatx16 S[2]; S[0] = fz; S[1] = fz;
    __builtin_amdgcn_s_setprio(1);
    sphase(lx, S);        // independent stream 1: S(i)
    pvphase(lxt, P);      // independent stream 2: PV(i-1)
    __builtin_amdgcn_s_setprio(0);
    expphase(S, P);       // S(i) latency covered by PV issue; P := P(i)

    asm volatile("" ::: "memory");
    __builtin_amdgcn_s_barrier();     // reads of X[i&1] and Xt[xtc] done
    if (i + 2 < NIT) { stgX(i + 2, i & 1); stgXT(i + 2, xtc); }
    xtc = (xtc == 2) ? 0 : xtc + 1;
  }
  // final PV(NIT-1)
  pvphase(&lds_xt[xtc][0], P);

  // epilogue
  float lt = lsum + __shfl_xor(lsum, 32);
  if (half == 0)
    l_part[(size_t)(b * NS + split) * Qq + qwbase + col] = lt;
  float* op = o_part + ((size_t)(b * NS + split) * Qq + qwbase) * Dd;
#pragma unroll
  for (int dn = 0; dn < 4; ++dn)
#pragma unroll
    for (int r = 0; r < 16; ++r) {
      int q = (r & 3) + 8 * (r >> 2) + 4 * half;
      op[(size_t)q * Dd + dn * 32 + col] = O[dn][r];
    }
}

// ---- K3: combine splits, normalize, trailing GEMM (32x32x16) -------------
// grid 256 = [b 2][qchunk 128 of 32 q]; block 256 = 4 waves (wave owns 64 E)
// lds_a: [32 q][16 units of 16B] stride 256B; unit u at (u&8)|((u^ (q&7))&7)
template <int NS>
__global__ __launch_bounds__(256) void k_comb(
    const float* __restrict__ o_part, const float* __restrict__ l_part,
    const unsigned short* __restrict__ wb, float* __restrict__ out) {
  __shared__ __align__(16) char lds_a[32 * 256];
  __shared__ float lds_linv[32];
  const int bid = blockIdx.x;
  const int b = bid >> 7, qc = bid & 127;
  const int qbase = qc * 32;
  const int tid = threadIdx.x;
  const int wave = tid >> 6, lane = tid & 63;
  const int col = lane & 31, half = lane >> 5;
  const int ck = col & 7;

  if (tid < 32) {
    float l = 0.f;
#pragma unroll
    for (int s = 0; s < NS; ++s)
      l += l_part[(size_t)(b * NS + s) * Qq + qbase + tid];
    lds_linv[tid] = 1.0f / l;
  }
  __syncthreads();

#pragma unroll
  for (int i = 0; i < 4; ++i) {
    int idx = i * 256 + tid;      // 1024 float4 units: q = idx>>5, d4 = idx&31
    int q = idx >> 5, d4 = idx & 31;
    float4 acc = make_float4(0.f, 0.f, 0.f, 0.f);
#pragma unroll
    for (int s = 0; s < NS; ++s) {
      float4 v = *(const float4*)(o_part + ((size_t)(b * NS + s) * Qq + qbase + q) * Dd + d4 * 4);
      acc.x += v.x; acc.y += v.y; acc.z += v.z; acc.w += v.w;
    }
    float li = lds_linv[q];
    int w = d4 >> 1;                          // 16B unit = 8 d values
    int pos = (w & 8) | ((w ^ (q & 7)) & 7);  // swizzle low 3 bits only
    *(uint2*)(lds_a + q * 256 + pos * 16 + (d4 & 1) * 8) =
        make_uint2(pk_bf(acc.x * li, acc.y * li), pk_bf(acc.z * li, acc.w * li));
  }
  __syncthreads();

  bf16x8 af[8];
#pragma unroll
  for (int s = 0; s < 8; ++s) {
    int u = 2 * s + half;
    int pos = (u & 8) | ((u ^ ck) & 7);
    af[s] = *(const bf16x8*)(lds_a + col * 256 + pos * 16);
  }

  const floatx16 fz = {0.f,0.f,0.f,0.f,0.f,0.f,0.f,0.f,0.f,0.f,0.f,0.f,0.f,0.f,0.f,0.f};
#pragma unroll
  for (int et = 0; et < 2; ++et) {
    floatx16 C = fz;
    int e_row = wave * 64 + et * 32 + col;
#pragma unroll
    for (int s = 0; s < 8; ++s) {
      bf16x8 bw = *(const bf16x8*)(wb + (size_t)e_row * Dd + s * 16 + half * 8);
      C = __builtin_amdgcn_mfma_f32_32x32x16_bf16(af[s], bw, C, 0, 0, 0);
    }
#pragma unroll
    for (int r = 0; r < 16; ++r) {
      int q = qbase + (r & 3) + 8 * (r >> 2) + 4 * half;
      out[((size_t)b * Qq + q) * Ee + wave * 64 + et * 32 + col] = C[r];
    }
  }
}

// ---- launcher ------------------------------------------------------------
extern "C" void kernel_launch(void* const* d_in, const int* in_sizes, int n_in,
                              void* d_out, int out_size, void* d_ws, size_t ws_size,
                              hipStream_t stream) {
  const float* x = (const float*)d_in[0];
  const float* gamma = (const float*)d_in[1];
  const float* beta = (const float*)d_in[2];
  const float* queries = (const float*)d_in[3];
  const float* W = (const float*)d_in[4];
  float* out = (float*)d_out;

  char* w = (char*)d_ws;
  unsigned* xn = (unsigned*)(w);                              // 8 MB
  unsigned short* xnT = (unsigned short*)(w + 8388608);       // 8 MB
  unsigned short* qb = (unsigned short*)(w + 16777216);       // 1 MB
  unsigned short* wb = (unsigned short*)(w + 17825792);       // 64 KB
  float* o_part = (float*)(w + 17891328);                     // 32 MB
  float* l_part = (float*)(w + 51445760);                     // 256 KB

  k_lnt<<<dim3(512), dim3(256), 0, stream>>>(x, gamma, beta, queries, W,
                                             xn, xnT, qb, wb);
  // 2 b x 32 qt x 8 splits = 512 blocks of 4 waves; split==bid%8 -> XCD-local L2
  k_attn<8, 4><<<dim3(512), dim3(256), 0, stream>>>((const unsigned short*)xn,
                                                    xnT, qb, o_part, l_part);
  k_comb<8><<<dim3(256), dim3(256), 0, stream>>>(o_part, l_part, wb, out);
}